// Round 14
// baseline (191.935 us; speedup 1.0000x reference)
//
#include <hip/hip_runtime.h>
#include <cstdint>

#define BB 8
#define PP 4096
#define DD 256
#define CC 1024

#define TILE_H 65536ull          // hi-plane 128-row tile: 128r x 256k x 2B
#define MARGIN 2.5e-4f

// ws layout (bytes)
#define WS_KEYS 0ull
#define WS_PK   65536ull         // part_k1: 8192 cells x 16 rb x 8B = 1MB
#define WS_PS   1114112ull       // part_s2: 8192 x 16 x 4B = 512KB
#define WS_CNT  1638400ull       // cnt[8] (pad 128)
#define WS_LIST 1638528ull       // blist[8][1024] int = 32KB
#define WS_XT   1671296ull       // 256 tiles x 64KB = 16MB
#define WS_WT   18448512ull      // 8 tiles x 64KB = 512KB
#define WS_NEED 18972800ull

typedef _Float16 f16x8 __attribute__((ext_vector_type(8)));
typedef float f32x16 __attribute__((ext_vector_type(16)));
typedef unsigned long long u64;

__device__ __forceinline__ void async_load16(const void* src, void* lds_dst) {
    __builtin_amdgcn_global_load_lds(
        (const __attribute__((address_space(1))) uint32_t*)src,
        (__attribute__((address_space(3))) uint32_t*)lds_dst,
        16, 0, 0);
}

__device__ __forceinline__ float keyscore(u64 k) {
    return __uint_as_float((unsigned int)(k >> 32));
}

// ---------------------------------------------------------------------------
// init argmax cells (fallback path only)
// ---------------------------------------------------------------------------
__global__ __launch_bounds__(256) void init_ws_kernel(u64* keys, int n) {
    int i = blockIdx.x * 256 + threadIdx.x;
    if (i < n) keys[i] = 0x00000000FFFFFFFFull;
}

// ---------------------------------------------------------------------------
// transform: fp32 [rows][256] -> fragment-ordered fp16 HI plane only.
// Chunk (k16, rt, slot) 16B at ((k16*4+rt)<<10) + slot*16;
// slot = (row&31) + 32*khalf; row = rt*32 + (slot&31), k = k16*16+(slot>>5)*8.
// grid 528: ids 0..511 -> x tile id>>1, h=id&1; 512..527 -> W tile.
// ---------------------------------------------------------------------------
__global__ __launch_bounds__(256) void transform_kernel(
    const float* __restrict__ x, const float* __restrict__ W,
    char* __restrict__ xT, char* __restrict__ wT)
{
    __shared__ float ls[64 * 260];

    const int id = blockIdx.x;
    const int t = threadIdx.x;
    const int tile = id >> 1;
    const int h = id & 1;
    const float* src;
    char* dstTile;
    if (tile < 256) {
        src = x + (size_t)tile * 128 * 256;
        dstTile = xT + (size_t)tile * TILE_H;
    } else {
        int cy = tile - 256;
        src = W + (size_t)cy * 128 * 256;
        dstTile = wT + (size_t)cy * TILE_H;
    }

    #pragma unroll
    for (int i = 0; i < 16; ++i) {
        int c = i * 256 + t;
        int row = c >> 6, kq = c & 63;
        float4 v = *reinterpret_cast<const float4*>(
            src + ((size_t)(h * 64 + row)) * 256 + kq * 4);
        *reinterpret_cast<float4*>(&ls[row * 260 + kq * 4]) = v;
    }
    __syncthreads();

    #pragma unroll
    for (int j = 0; j < 8; ++j) {
        int q2 = j * 256 + t;             // 0..2047
        int slot = q2 & 63;
        int rtl = (q2 >> 6) & 1;
        int k16 = q2 >> 7;                // 0..15
        int rowl = rtl * 32 + (slot & 31);
        int k = k16 * 16 + (slot >> 5) * 8;
        const float* p = &ls[rowl * 260 + k];
        f16x8 o;
        #pragma unroll
        for (int i = 0; i < 8; ++i) o[i] = (_Float16)p[i];
        int rt = h * 2 + rtl;
        size_t off = ((size_t)(k16 * 4 + rt) << 10) + (size_t)slot * 16;
        *reinterpret_cast<f16x8*>(dstTile + off) = o;
    }
}

// ---------------------------------------------------------------------------
// pass-1: single-plane fp16 MFMA scores_hi = relu(xh @ wh^T) + per-column
// top-2 partials. Block 256 rows x 128 cols, 4 waves (wm=wid), each wave
// 64 rows x 128 cols: acc[2][4] = 128 VGPR. BK=16, 16 stages, ring-3 LDS
// (3 x 12KB), counted vmcnt(3), one barrier/stage (r12-proven skeleton).
// Writes part_k1/part_s2 [cell*16 + q] (q = 256-row block index).
// ---------------------------------------------------------------------------
__global__ __launch_bounds__(256, 2) void pass1_kernel(
    const char* __restrict__ xT, const char* __restrict__ wT,
    u64* __restrict__ part_k1, float* __restrict__ part_s2)
{
    __shared__ __align__(16) char lds[3][12288];   // [buf][A 8KB | B 4KB]

    const int tid = threadIdx.x;
    const int lane = tid & 63;
    const int wm = tid >> 6;            // 0..3, rows wm*64..+63
    const int q  = blockIdx.x;          // 0..15 (256-row group)
    const int cy = blockIdx.y;          // 0..7  (128-col group)
    const int b  = blockIdx.z;
    const int p0 = q * 256;
    const int c0 = cy * 128;

    const char* aTile0 = xT + ((size_t)(b * 32 + q * 2)) * TILE_H;
    const char* bTile  = wT + (size_t)cy * TILE_H;

    // staging: 12 chunks/stage (A 0..7, B 8..11); wave wm does 3: wm*3+i
    const char* sSrc[3];
    int sDst[3];
    #pragma unroll
    for (int i = 0; i < 3; ++i) {
        int c = wm * 3 + i;
        if (c < 8) {
            sSrc[i] = aTile0 + (size_t)(c >> 2) * TILE_H
                      + (size_t)((c & 3) << 10) + (size_t)lane * 16;
            sDst[i] = c << 10;
        } else {
            sSrc[i] = bTile + (size_t)((c - 8) << 10) + (size_t)lane * 16;
            sDst[i] = 8192 + ((c - 8) << 10);
        }
    }

    f32x16 zero;
    #pragma unroll
    for (int i = 0; i < 16; ++i) zero[i] = 0.f;
    f32x16 acc[2][4];
    #pragma unroll
    for (int i = 0; i < 2; ++i)
        #pragma unroll
        for (int j = 0; j < 4; ++j) acc[i][j] = zero;

    const int aOff0 = ((wm * 2 + 0) << 10) + lane * 16;
    const int aOff1 = ((wm * 2 + 1) << 10) + lane * 16;

    // prologue: stage 0 -> buf0, stage 1 -> buf1 (6 loads/thread in flight)
    #pragma unroll
    for (int i = 0; i < 3; ++i) async_load16(sSrc[i], &lds[0][sDst[i]]);
    #pragma unroll
    for (int i = 0; i < 3; ++i) async_load16(sSrc[i] + 4096, &lds[1][sDst[i]]);

    #pragma unroll
    for (int st = 0; st < 16; ++st) {
        const int buf = st % 3;
        if (st < 15) asm volatile("s_waitcnt vmcnt(3)" ::: "memory");
        else         asm volatile("s_waitcnt vmcnt(0)" ::: "memory");
        __builtin_amdgcn_s_barrier();

        const char* L = &lds[buf][0];
        f16x8 a[2], bv[4];
        a[0] = *reinterpret_cast<const f16x8*>(L + aOff0);
        a[1] = *reinterpret_cast<const f16x8*>(L + aOff1);
        #pragma unroll
        for (int ct = 0; ct < 4; ++ct)
            bv[ct] = *reinterpret_cast<const f16x8*>(L + 8192 + (ct << 10) + lane * 16);

        if (st + 2 < 16) {
            const int nb = (st + 2) % 3;
            #pragma unroll
            for (int i = 0; i < 3; ++i)
                async_load16(sSrc[i] + (size_t)(st + 2) * 4096, &lds[nb][sDst[i]]);
        }

        asm volatile("s_waitcnt lgkmcnt(0)" ::: "memory");
        __builtin_amdgcn_s_setprio(1);
        #pragma unroll
        for (int rt = 0; rt < 2; ++rt)
            #pragma unroll
            for (int ct = 0; ct < 4; ++ct)
                acc[rt][ct] = __builtin_amdgcn_mfma_f32_32x32x16_f16(
                    a[rt], bv[ct], acc[rt][ct], 0, 0, 0);
        __builtin_amdgcn_s_setprio(0);
    }

    // ---- epilogue: per-column top-2 partial over this block's 256 rows ----
    __syncthreads();
    u64*  pk = reinterpret_cast<u64*>(&lds[0][0]);      // [4][128]
    float* ps = reinterpret_cast<float*>(&lds[0][4096]); // [4][128]

    #pragma unroll
    for (int ct = 0; ct < 4; ++ct) {
        u64 k1 = 0ull;
        float s2 = 0.f;
        #pragma unroll
        for (int rt = 0; rt < 2; ++rt) {
            f32x16 v16 = acc[rt][ct];
            #pragma unroll
            for (int reg = 0; reg < 16; ++reg) {
                float v = fmaxf(v16[reg], 0.f);
                int prow = p0 + wm * 64 + rt * 32 +
                           (reg & 3) + 8 * (reg >> 2) + 4 * (lane >> 5);
                u64 key = ((u64)__float_as_uint(v) << 32) |
                          (unsigned int)(0xFFFFFFFFu - (unsigned int)prow);
                if (key > k1) { s2 = fmaxf(s2, keyscore(k1)); k1 = key; }
                else          { s2 = fmaxf(s2, v); }
            }
        }
        u64 ok = __shfl_xor(k1, 32, 64);
        float os2 = __shfl_xor(s2, 32, 64);
        if (ok > k1) { s2 = fmaxf(fmaxf(s2, os2), keyscore(k1)); k1 = ok; }
        else         { s2 = fmaxf(fmaxf(s2, os2), keyscore(ok)); }
        if (lane < 32) {
            int col = ct * 32 + lane;
            pk[wm * 128 + col] = k1;
            ps[wm * 128 + col] = s2;
        }
    }
    __syncthreads();
    if (tid < 128) {
        int col = tid;
        u64 K = pk[col];
        float S = ps[col];
        #pragma unroll
        for (int w2 = 1; w2 < 4; ++w2) {
            u64 k2 = pk[w2 * 128 + col];
            float s2b = ps[w2 * 128 + col];
            if (k2 > K) { S = fmaxf(fmaxf(S, s2b), keyscore(K)); K = k2; }
            else        { S = fmaxf(fmaxf(S, s2b), keyscore(k2)); }
        }
        int cell = b * CC + c0 + col;
        part_k1[(size_t)cell * 16 + q] = K;
        part_s2[(size_t)cell * 16 + q] = S;
    }
}

// ---------------------------------------------------------------------------
// finalize: merge 16 row-block partials per cell, margin-flag, write keys.
// Unflagged: keys = hi-argmax key. Flagged: keys = 0, append to per-b list.
// grid 32 x 256.
// ---------------------------------------------------------------------------
__global__ __launch_bounds__(256) void finalize_kernel(
    const u64* __restrict__ part_k1, const float* __restrict__ part_s2,
    u64* __restrict__ keys, int* __restrict__ cnt, int* __restrict__ blist)
{
    int cell = blockIdx.x * 256 + threadIdx.x;   // 0..8191
    u64 K = part_k1[(size_t)cell * 16];
    float S = part_s2[(size_t)cell * 16];
    #pragma unroll
    for (int q = 1; q < 16; ++q) {
        u64 k2 = part_k1[(size_t)cell * 16 + q];
        float s2b = part_s2[(size_t)cell * 16 + q];
        if (k2 > K) { S = fmaxf(fmaxf(S, s2b), keyscore(K)); K = k2; }
        else        { S = fmaxf(fmaxf(S, s2b), keyscore(k2)); }
    }
    float s1 = keyscore(K);
    bool flag = (s1 - S < MARGIN) || (s1 < MARGIN);
    if (!flag) {
        keys[cell] = K;
    } else {
        keys[cell] = 0ull;
        int b = cell >> 10;
        int i = atomicAdd(&cnt[b], 1);
        blist[b * 1024 + i] = cell & (CC - 1);
    }
}

// ---------------------------------------------------------------------------
// rescue v2: exact fp32 scores for flagged cells. Block (rc, b) stages
// x[b, rc*64..+63, :] in LDS once; then WAVE-PER-COLUMN (j = wid, j += 4),
// no block barriers in the loop: lane = row, dot = 64 x float4 (LDS stride
// 260 floats -> bank start (r + kq) % 32, 2-way = free; W row = uniform
// float4 broadcasts, L1-resident), 4 independent FMA chains, 6-step
// shfl_xor max-reduce, one atomicMax per (wave, column).
// ---------------------------------------------------------------------------
__global__ __launch_bounds__(256, 2) void rescue_kernel(
    const float* __restrict__ x, const float* __restrict__ W,
    const int* __restrict__ cnt, const int* __restrict__ blist,
    u64* __restrict__ keys)
{
    __shared__ float xs[64 * 260];   // row stride 260 floats (1040B, 16B-aligned)

    const int rc = blockIdx.x;       // 0..63 row chunk
    const int b  = blockIdx.y;
    const int n = cnt[b];
    if (n == 0) return;
    const int tid = threadIdx.x;
    const int lane = tid & 63;
    const int wid = tid >> 6;

    const float* xb = x + ((size_t)b * PP + (size_t)rc * 64) * DD;
    #pragma unroll
    for (int i = 0; i < 16; ++i) {
        int idx = i * 256 + tid;     // 4096 float4 chunks
        int r = idx >> 6, c4 = (idx & 63) * 4;
        float4 v = *reinterpret_cast<const float4*>(xb + (size_t)r * DD + c4);
        *reinterpret_cast<float4*>(&xs[r * 260 + c4]) = v;
    }
    __syncthreads();

    const float4* xr = reinterpret_cast<const float4*>(&xs[lane * 260]);
    const int p = rc * 64 + lane;
    for (int j = wid; j < n; j += 4) {
        const int c = blist[b * 1024 + j];
        const float4* wr = reinterpret_cast<const float4*>(W + (size_t)c * DD);
        float a0 = 0.f, a1 = 0.f, a2 = 0.f, a3 = 0.f;
        #pragma unroll
        for (int k = 0; k < 64; ++k) {
            float4 wv = wr[k];
            float4 xv = xr[k];
            a0 = fmaf(xv.x, wv.x, a0);
            a1 = fmaf(xv.y, wv.y, a1);
            a2 = fmaf(xv.z, wv.z, a2);
            a3 = fmaf(xv.w, wv.w, a3);
        }
        float s = (a0 + a1) + (a2 + a3);
        float v = fmaxf(s, 0.f);
        u64 key = ((u64)__float_as_uint(v) << 32) |
                  (unsigned int)(0xFFFFFFFFu - (unsigned int)p);
        #pragma unroll
        for (int off = 1; off < 64; off <<= 1) {
            u64 o = __shfl_xor(key, off, 64);
            key = key > o ? key : o;
        }
        if (lane == 0) atomicMax(&keys[b * CC + c], key);
    }
}

// ---------------------------------------------------------------------------
// scatter: out[b, argmax_p(b,c), :] += W[c, :]
// ---------------------------------------------------------------------------
__global__ __launch_bounds__(64) void scatter_kernel(
    const u64* __restrict__ keys,
    const float* __restrict__ W,
    float* __restrict__ out)
{
    const int cell = blockIdx.x;
    const int c = cell & (CC - 1);
    const int b = cell >> 10;
    u64 key = keys[cell];
    unsigned int p = (0xFFFFFFFFu - (unsigned int)(key & 0xFFFFFFFFull)) & (PP - 1);

    const float* wrow = W + (size_t)c * DD;
    float* orow = out + ((size_t)b * PP + p) * DD;
    const int t = threadIdx.x;
    #pragma unroll
    for (int u = 0; u < 4; u++) {
        int idx = u * 64 + t;
        atomicAdd(&orow[idx], wrow[idx]);
    }
}

// ---------------------------------------------------------------------------
// fallback (ws too small): round-2 in-kernel-conversion kernel (verified)
// ---------------------------------------------------------------------------
__global__ __launch_bounds__(256, 2) void gemm_argmax_conv_kernel(
    const float* __restrict__ x, const float* __restrict__ W,
    u64* __restrict__ keys)
{
    __shared__ f16x8 lA[4][4][2][64];
    __shared__ f16x8 lB[4][4][2][64];

    const int tid = threadIdx.x;
    const int lane = tid & 63;
    const int w = tid >> 6;
    const int wy = w >> 1, wx = w & 1;
    const int p0 = blockIdx.x * 128;
    const int c0 = blockIdx.y * 128;
    const int b  = blockIdx.z;

    const float* xb = x + (size_t)b * PP * DD;

    f32x16 zero;
    #pragma unroll
    for (int i = 0; i < 16; ++i) zero[i] = 0.f;
    f32x16 acc_hi[2][2], acc_lo[2][2];
    #pragma unroll
    for (int i = 0; i < 2; ++i)
        #pragma unroll
        for (int j = 0; j < 2; ++j) { acc_hi[i][j] = zero; acc_lo[i][j] = zero; }

    for (int st = 0; st < 4; ++st) {
        const int k0 = st * 64;
        float4 gA[8], gB[8];
        #pragma unroll
        for (int v = 0; v < 4; ++v) {
            int pi = tid + 256 * v;
            int r  = pi >> 3;
            int ck = (pi & 7) * 8;
            const float* pa = xb + (size_t)(p0 + r) * DD + k0 + ck;
            gA[2 * v]     = *reinterpret_cast<const float4*>(pa);
            gA[2 * v + 1] = *reinterpret_cast<const float4*>(pa + 4);
            const float* pb = W + (size_t)(c0 + r) * DD + k0 + ck;
            gB[2 * v]     = *reinterpret_cast<const float4*>(pb);
            gB[2 * v + 1] = *reinterpret_cast<const float4*>(pb + 4);
        }
        __syncthreads();
        #pragma unroll
        for (int v = 0; v < 4; ++v) {
            int pi = tid + 256 * v;
            int r  = pi >> 3;
            int ph = pi & 7;
            int kk = ph >> 1;
            int half = ph & 1;
            int slot = (r & 31) + 32 * half;
            int rtp = r >> 5;
            float va[8] = {gA[2*v].x, gA[2*v].y, gA[2*v].z, gA[2*v].w,
                           gA[2*v+1].x, gA[2*v+1].y, gA[2*v+1].z, gA[2*v+1].w};
            f16x8 h1, h2;
            #pragma unroll
            for (int i = 0; i < 8; ++i) {
                _Float16 h = (_Float16)va[i];
                h1[i] = h;
                h2[i] = (_Float16)((va[i] - (float)h) * 4096.0f);
            }
            lA[kk][rtp][0][slot] = h1;
            lA[kk][rtp][1][slot] = h2;
            float vb[8] = {gB[2*v].x, gB[2*v].y, gB[2*v].z, gB[2*v].w,
                           gB[2*v+1].x, gB[2*v+1].y, gB[2*v+1].z, gB[2*v+1].w};
            f16x8 g1, g2;
            #pragma unroll
            for (int i = 0; i < 8; ++i) {
                _Float16 h = (_Float16)vb[i];
                g1[i] = h;
                g2[i] = (_Float16)((vb[i] - (float)h) * 4096.0f);
            }
            lB[kk][rtp][0][slot] = g1;
            lB[kk][rtp][1][slot] = g2;
        }
        __syncthreads();
        #pragma unroll
        for (int kk = 0; kk < 4; ++kk) {
            f16x8 xa[2][2], wb2[2][2];
            #pragma unroll
            for (int rt = 0; rt < 2; ++rt) {
                xa[rt][0] = lA[kk][wy * 2 + rt][0][lane];
                xa[rt][1] = lA[kk][wy * 2 + rt][1][lane];
            }
            #pragma unroll
            for (int ct = 0; ct < 2; ++ct) {
                wb2[ct][0] = lB[kk][wx * 2 + ct][0][lane];
                wb2[ct][1] = lB[kk][wx * 2 + ct][1][lane];
            }
            #pragma unroll
            for (int rt = 0; rt < 2; ++rt)
                #pragma unroll
                for (int ct = 0; ct < 2; ++ct) {
                    acc_hi[rt][ct] = __builtin_amdgcn_mfma_f32_32x32x16_f16(
                        xa[rt][0], wb2[ct][0], acc_hi[rt][ct], 0, 0, 0);
                    acc_lo[rt][ct] = __builtin_amdgcn_mfma_f32_32x32x16_f16(
                        xa[rt][0], wb2[ct][1], acc_lo[rt][ct], 0, 0, 0);
                    acc_lo[rt][ct] = __builtin_amdgcn_mfma_f32_32x32x16_f16(
                        xa[rt][1], wb2[ct][0], acc_lo[rt][ct], 0, 0, 0);
                }
        }
    }

    u64* smax = reinterpret_cast<u64*>(&lA[0][0][0][0]);
    __syncthreads();
    if (tid < 128) smax[tid] = 0ull;
    __syncthreads();

    #pragma unroll
    for (int ct = 0; ct < 2; ++ct) {
        u64 bk = 0ull;
        #pragma unroll
        for (int rt = 0; rt < 2; ++rt) {
            f32x16 h = acc_hi[rt][ct];
            f32x16 l = acc_lo[rt][ct];
            #pragma unroll
            for (int reg = 0; reg < 16; ++reg) {
                float v = fmaxf(h[reg] + l[reg] * (1.0f / 4096.0f), 0.f);
                int prow = p0 + (wy * 2 + rt) * 32 +
                           (reg & 3) + 8 * (reg >> 2) + 4 * (lane >> 5);
                u64 key = ((u64)__float_as_uint(v) << 32) |
                          (unsigned int)(0xFFFFFFFFu - (unsigned int)prow);
                bk = bk > key ? bk : key;
            }
        }
        u64 other = __shfl_xor(bk, 32, 64);
        bk = bk > other ? bk : other;
        if (lane < 32) {
            int col = (wx * 2 + ct) * 32 + (lane & 31);
            atomicMax(&smax[col], bk);
        }
    }
    __syncthreads();
    if (tid < 128) {
        atomicMax(&keys[(size_t)b * CC + c0 + tid], smax[tid]);
    }
}

extern "C" void kernel_launch(void* const* d_in, const int* in_sizes, int n_in,
                              void* d_out, int out_size, void* d_ws, size_t ws_size,
                              hipStream_t stream) {
    const float* x = (const float*)d_in[0];   // [B, P, D] fp32
    const float* W = (const float*)d_in[1];   // [C, D]    fp32
    float* out = (float*)d_out;

    char* wsb = (char*)d_ws;
    u64* keys    = (u64*)(wsb + WS_KEYS);
    u64* part_k1 = (u64*)(wsb + WS_PK);
    float* part_s2 = (float*)(wsb + WS_PS);
    int* cnt     = (int*)(wsb + WS_CNT);
    int* blist   = (int*)(wsb + WS_LIST);
    char* xT     = wsb + WS_XT;
    char* wT     = wsb + WS_WT;

    hipMemsetAsync(d_out, 0, (size_t)out_size * sizeof(float), stream);

    if (ws_size >= WS_NEED) {
        hipMemsetAsync(cnt, 0, 32, stream);
        transform_kernel<<<528, 256, 0, stream>>>(x, W, xT, wT);
        {
            dim3 grid(PP / 256, CC / 128, BB);
            pass1_kernel<<<grid, 256, 0, stream>>>(xT, wT, part_k1, part_s2);
        }
        finalize_kernel<<<32, 256, 0, stream>>>(part_k1, part_s2, keys, cnt, blist);
        {
            dim3 grid(64, BB);
            rescue_kernel<<<grid, 256, 0, stream>>>(x, W, cnt, blist, keys);
        }
    } else {
        int n = BB * CC;
        init_ws_kernel<<<(n + 255) / 256, 256, 0, stream>>>(keys, n);
        dim3 grid(PP / 128, CC / 128, BB);
        gemm_argmax_conv_kernel<<<grid, 256, 0, stream>>>(x, W, keys);
    }

    {
        dim3 grid(BB * CC);
        scatter_kernel<<<grid, 64, 0, stream>>>(keys, W, out);
    }
}

// Round 15
// 112.088 us; speedup vs baseline: 1.7124x; 1.7124x over previous
//
#include <hip/hip_runtime.h>
#include <cstdint>

#define BB 8
#define PP 4096
#define DD 256
#define CC 1024

#define TILE_H 65536ull          // hi-plane 128-row tile: 128r x 256k x 2B
#define MARGIN 1.2e-4f           // gap-error max ~3.6e-5 (3.3x headroom)

// ws layout (bytes)
#define WS_KEYS 0ull
#define WS_PK   65536ull         // part_k1: 8192 cells x 16 rb x 8B = 1MB
#define WS_PS   1114112ull       // part_s2: 8192 x 16 x 4B = 512KB
#define WS_CNT  1638400ull       // cnt[8] (pad 128)
#define WS_LIST 1638528ull       // blist[8][1024] int = 32KB
#define WS_XT   1671296ull       // 256 tiles x 64KB = 16MB
#define WS_WT   18448512ull      // 8 tiles x 64KB = 512KB
#define WS_NEED 18972800ull

typedef _Float16 f16x8 __attribute__((ext_vector_type(8)));
typedef float f32x16 __attribute__((ext_vector_type(16)));
typedef unsigned long long u64;

__device__ __forceinline__ void async_load16(const void* src, void* lds_dst) {
    __builtin_amdgcn_global_load_lds(
        (const __attribute__((address_space(1))) uint32_t*)src,
        (__attribute__((address_space(3))) uint32_t*)lds_dst,
        16, 0, 0);
}

__device__ __forceinline__ float keyscore(u64 k) {
    return __uint_as_float((unsigned int)(k >> 32));
}

// ---------------------------------------------------------------------------
// init argmax cells (fallback path only)
// ---------------------------------------------------------------------------
__global__ __launch_bounds__(256) void init_ws_kernel(u64* keys, int n) {
    int i = blockIdx.x * 256 + threadIdx.x;
    if (i < n) keys[i] = 0x00000000FFFFFFFFull;
}

// ---------------------------------------------------------------------------
// transform: fp32 [rows][256] -> fragment-ordered fp16 HI plane only.
// Chunk (k16, rt, slot) 16B at ((k16*4+rt)<<10) + slot*16;
// slot = (row&31) + 32*khalf; row = rt*32 + (slot&31), k = k16*16+(slot>>5)*8.
// grid 528: ids 0..511 -> x tile id>>1, h=id&1; 512..527 -> W tile.
// ---------------------------------------------------------------------------
__global__ __launch_bounds__(256) void transform_kernel(
    const float* __restrict__ x, const float* __restrict__ W,
    char* __restrict__ xT, char* __restrict__ wT)
{
    __shared__ float ls[64 * 260];

    const int id = blockIdx.x;
    const int t = threadIdx.x;
    const int tile = id >> 1;
    const int h = id & 1;
    const float* src;
    char* dstTile;
    if (tile < 256) {
        src = x + (size_t)tile * 128 * 256;
        dstTile = xT + (size_t)tile * TILE_H;
    } else {
        int cy = tile - 256;
        src = W + (size_t)cy * 128 * 256;
        dstTile = wT + (size_t)cy * TILE_H;
    }

    #pragma unroll
    for (int i = 0; i < 16; ++i) {
        int c = i * 256 + t;
        int row = c >> 6, kq = c & 63;
        float4 v = *reinterpret_cast<const float4*>(
            src + ((size_t)(h * 64 + row)) * 256 + kq * 4);
        *reinterpret_cast<float4*>(&ls[row * 260 + kq * 4]) = v;
    }
    __syncthreads();

    #pragma unroll
    for (int j = 0; j < 8; ++j) {
        int q2 = j * 256 + t;             // 0..2047
        int slot = q2 & 63;
        int rtl = (q2 >> 6) & 1;
        int k16 = q2 >> 7;                // 0..15
        int rowl = rtl * 32 + (slot & 31);
        int k = k16 * 16 + (slot >> 5) * 8;
        const float* p = &ls[rowl * 260 + k];
        f16x8 o;
        #pragma unroll
        for (int i = 0; i < 8; ++i) o[i] = (_Float16)p[i];
        int rt = h * 2 + rtl;
        size_t off = ((size_t)(k16 * 4 + rt) << 10) + (size_t)slot * 16;
        *reinterpret_cast<f16x8*>(dstTile + off) = o;
    }
}

// ---------------------------------------------------------------------------
// pass-1: single-plane fp16 MFMA scores_hi = relu(xh @ wh^T) + per-column
// top-2 partials. (r13-verified: absmax 0 with rescue.) Block 256x128,
// 4 waves, BK=16, ring-3 LDS, counted vmcnt(3), one barrier/stage.
// ---------------------------------------------------------------------------
__global__ __launch_bounds__(256, 2) void pass1_kernel(
    const char* __restrict__ xT, const char* __restrict__ wT,
    u64* __restrict__ part_k1, float* __restrict__ part_s2)
{
    __shared__ __align__(16) char lds[3][12288];   // [buf][A 8KB | B 4KB]

    const int tid = threadIdx.x;
    const int lane = tid & 63;
    const int wm = tid >> 6;            // 0..3, rows wm*64..+63
    const int q  = blockIdx.x;          // 0..15 (256-row group)
    const int cy = blockIdx.y;          // 0..7  (128-col group)
    const int b  = blockIdx.z;
    const int p0 = q * 256;
    const int c0 = cy * 128;

    const char* aTile0 = xT + ((size_t)(b * 32 + q * 2)) * TILE_H;
    const char* bTile  = wT + (size_t)cy * TILE_H;

    const char* sSrc[3];
    int sDst[3];
    #pragma unroll
    for (int i = 0; i < 3; ++i) {
        int c = wm * 3 + i;
        if (c < 8) {
            sSrc[i] = aTile0 + (size_t)(c >> 2) * TILE_H
                      + (size_t)((c & 3) << 10) + (size_t)lane * 16;
            sDst[i] = c << 10;
        } else {
            sSrc[i] = bTile + (size_t)((c - 8) << 10) + (size_t)lane * 16;
            sDst[i] = 8192 + ((c - 8) << 10);
        }
    }

    f32x16 zero;
    #pragma unroll
    for (int i = 0; i < 16; ++i) zero[i] = 0.f;
    f32x16 acc[2][4];
    #pragma unroll
    for (int i = 0; i < 2; ++i)
        #pragma unroll
        for (int j = 0; j < 4; ++j) acc[i][j] = zero;

    const int aOff0 = ((wm * 2 + 0) << 10) + lane * 16;
    const int aOff1 = ((wm * 2 + 1) << 10) + lane * 16;

    #pragma unroll
    for (int i = 0; i < 3; ++i) async_load16(sSrc[i], &lds[0][sDst[i]]);
    #pragma unroll
    for (int i = 0; i < 3; ++i) async_load16(sSrc[i] + 4096, &lds[1][sDst[i]]);

    #pragma unroll
    for (int st = 0; st < 16; ++st) {
        const int buf = st % 3;
        if (st < 15) asm volatile("s_waitcnt vmcnt(3)" ::: "memory");
        else         asm volatile("s_waitcnt vmcnt(0)" ::: "memory");
        __builtin_amdgcn_s_barrier();

        const char* L = &lds[buf][0];
        f16x8 a[2], bv[4];
        a[0] = *reinterpret_cast<const f16x8*>(L + aOff0);
        a[1] = *reinterpret_cast<const f16x8*>(L + aOff1);
        #pragma unroll
        for (int ct = 0; ct < 4; ++ct)
            bv[ct] = *reinterpret_cast<const f16x8*>(L + 8192 + (ct << 10) + lane * 16);

        if (st + 2 < 16) {
            const int nb = (st + 2) % 3;
            #pragma unroll
            for (int i = 0; i < 3; ++i)
                async_load16(sSrc[i] + (size_t)(st + 2) * 4096, &lds[nb][sDst[i]]);
        }

        asm volatile("s_waitcnt lgkmcnt(0)" ::: "memory");
        __builtin_amdgcn_s_setprio(1);
        #pragma unroll
        for (int rt = 0; rt < 2; ++rt)
            #pragma unroll
            for (int ct = 0; ct < 4; ++ct)
                acc[rt][ct] = __builtin_amdgcn_mfma_f32_32x32x16_f16(
                    a[rt], bv[ct], acc[rt][ct], 0, 0, 0);
        __builtin_amdgcn_s_setprio(0);
    }

    // ---- epilogue: per-column top-2 partial over this block's 256 rows ----
    __syncthreads();
    u64*  pk = reinterpret_cast<u64*>(&lds[0][0]);      // [4][128]
    float* ps = reinterpret_cast<float*>(&lds[0][4096]); // [4][128]

    #pragma unroll
    for (int ct = 0; ct < 4; ++ct) {
        u64 k1 = 0ull;
        float s2 = 0.f;
        #pragma unroll
        for (int rt = 0; rt < 2; ++rt) {
            f32x16 v16 = acc[rt][ct];
            #pragma unroll
            for (int reg = 0; reg < 16; ++reg) {
                float v = fmaxf(v16[reg], 0.f);
                int prow = p0 + wm * 64 + rt * 32 +
                           (reg & 3) + 8 * (reg >> 2) + 4 * (lane >> 5);
                u64 key = ((u64)__float_as_uint(v) << 32) |
                          (unsigned int)(0xFFFFFFFFu - (unsigned int)prow);
                if (key > k1) { s2 = fmaxf(s2, keyscore(k1)); k1 = key; }
                else          { s2 = fmaxf(s2, v); }
            }
        }
        u64 ok = __shfl_xor(k1, 32, 64);
        float os2 = __shfl_xor(s2, 32, 64);
        if (ok > k1) { s2 = fmaxf(fmaxf(s2, os2), keyscore(k1)); k1 = ok; }
        else         { s2 = fmaxf(fmaxf(s2, os2), keyscore(ok)); }
        if (lane < 32) {
            int col = ct * 32 + lane;
            pk[wm * 128 + col] = k1;
            ps[wm * 128 + col] = s2;
        }
    }
    __syncthreads();
    if (tid < 128) {
        int col = tid;
        u64 K = pk[col];
        float S = ps[col];
        #pragma unroll
        for (int w2 = 1; w2 < 4; ++w2) {
            u64 k2 = pk[w2 * 128 + col];
            float s2b = ps[w2 * 128 + col];
            if (k2 > K) { S = fmaxf(fmaxf(S, s2b), keyscore(K)); K = k2; }
            else        { S = fmaxf(fmaxf(S, s2b), keyscore(k2)); }
        }
        int cell = b * CC + c0 + col;
        part_k1[(size_t)cell * 16 + q] = K;
        part_s2[(size_t)cell * 16 + q] = S;
    }
}

// ---------------------------------------------------------------------------
// finalize: merge 16 row-block partials per cell, margin-flag, write keys.
// Overflow guard: if a b's list is full, keep the approximate key (no OOB).
// ---------------------------------------------------------------------------
__global__ __launch_bounds__(256) void finalize_kernel(
    const u64* __restrict__ part_k1, const float* __restrict__ part_s2,
    u64* __restrict__ keys, int* __restrict__ cnt, int* __restrict__ blist)
{
    int cell = blockIdx.x * 256 + threadIdx.x;   // 0..8191
    u64 K = part_k1[(size_t)cell * 16];
    float S = part_s2[(size_t)cell * 16];
    #pragma unroll
    for (int q = 1; q < 16; ++q) {
        u64 k2 = part_k1[(size_t)cell * 16 + q];
        float s2b = part_s2[(size_t)cell * 16 + q];
        if (k2 > K) { S = fmaxf(fmaxf(S, s2b), keyscore(K)); K = k2; }
        else        { S = fmaxf(fmaxf(S, s2b), keyscore(k2)); }
    }
    float s1 = keyscore(K);
    bool flag = (s1 - S < MARGIN) || (s1 < MARGIN);
    if (flag) {
        int b = cell >> 10;
        int i = atomicAdd(&cnt[b], 1);
        if (i < 1024) {
            keys[cell] = 0ull;
            blist[b * 1024 + i] = cell & (CC - 1);
            return;
        }
    }
    keys[cell] = K;
}

// ---------------------------------------------------------------------------
// rescue v3: exact fp32 scores for flagged cells, 8-COLUMN BATCHES per wave.
// Block (rc, b) stages x[b, rc*64..+63, :] in LDS once. Each wave takes 8
// columns at a time (jb = wid*8; jb += 32): x float4 read from LDS ONCE per
// batch (8x fewer LDS reads than v2 — v2 was LDS-issue-bound at 768
// cyc/column), 8 W rows streamed as uniform float4 loads, 32 acc registers,
// no barriers in the loop. Tail: j >= n recomputes column blist[0]
// (atomicMax idempotent).
// ---------------------------------------------------------------------------
__global__ __launch_bounds__(256, 2) void rescue_kernel(
    const float* __restrict__ x, const float* __restrict__ W,
    const int* __restrict__ cnt, const int* __restrict__ blist,
    u64* __restrict__ keys)
{
    __shared__ float xs[64 * 260];   // row stride 260 floats (16B-aligned)

    const int rc = blockIdx.x;       // 0..63 row chunk
    const int b  = blockIdx.y;
    int n = cnt[b];
    if (n == 0) return;
    if (n > 1024) n = 1024;
    const int tid = threadIdx.x;
    const int lane = tid & 63;
    const int wid = tid >> 6;

    const float* xb = x + ((size_t)b * PP + (size_t)rc * 64) * DD;
    #pragma unroll
    for (int i = 0; i < 16; ++i) {
        int idx = i * 256 + tid;     // 4096 float4 chunks
        int r = idx >> 6, c4 = (idx & 63) * 4;
        float4 v = *reinterpret_cast<const float4*>(xb + (size_t)r * DD + c4);
        *reinterpret_cast<float4*>(&xs[r * 260 + c4]) = v;
    }
    __syncthreads();

    const float4* xr = reinterpret_cast<const float4*>(&xs[lane * 260]);
    const int p = rc * 64 + lane;
    const int base = b * 1024;

    for (int jb = wid * 8; jb < n; jb += 32) {
        const float4* wr0 = reinterpret_cast<const float4*>(W + (size_t)blist[base + ((jb + 0) < n ? jb + 0 : 0)] * DD);
        const float4* wr1 = reinterpret_cast<const float4*>(W + (size_t)blist[base + ((jb + 1) < n ? jb + 1 : 0)] * DD);
        const float4* wr2 = reinterpret_cast<const float4*>(W + (size_t)blist[base + ((jb + 2) < n ? jb + 2 : 0)] * DD);
        const float4* wr3 = reinterpret_cast<const float4*>(W + (size_t)blist[base + ((jb + 3) < n ? jb + 3 : 0)] * DD);
        const float4* wr4 = reinterpret_cast<const float4*>(W + (size_t)blist[base + ((jb + 4) < n ? jb + 4 : 0)] * DD);
        const float4* wr5 = reinterpret_cast<const float4*>(W + (size_t)blist[base + ((jb + 5) < n ? jb + 5 : 0)] * DD);
        const float4* wr6 = reinterpret_cast<const float4*>(W + (size_t)blist[base + ((jb + 6) < n ? jb + 6 : 0)] * DD);
        const float4* wr7 = reinterpret_cast<const float4*>(W + (size_t)blist[base + ((jb + 7) < n ? jb + 7 : 0)] * DD);

        float acc[8][2];
        #pragma unroll
        for (int u = 0; u < 8; ++u) { acc[u][0] = 0.f; acc[u][1] = 0.f; }

        #pragma unroll 4
        for (int k = 0; k < 64; ++k) {
            float4 xv = xr[k];
            #define DOT(u, WR)                                             \
                do {                                                       \
                    float4 wv = WR[k];                                     \
                    acc[u][0] = fmaf(xv.x, wv.x, acc[u][0]);               \
                    acc[u][1] = fmaf(xv.y, wv.y, acc[u][1]);               \
                    acc[u][0] = fmaf(xv.z, wv.z, acc[u][0]);               \
                    acc[u][1] = fmaf(xv.w, wv.w, acc[u][1]);               \
                } while (0)
            DOT(0, wr0); DOT(1, wr1); DOT(2, wr2); DOT(3, wr3);
            DOT(4, wr4); DOT(5, wr5); DOT(6, wr6); DOT(7, wr7);
            #undef DOT
        }

        #pragma unroll
        for (int u = 0; u < 8; ++u) {
            int j = jb + u;
            int c = blist[base + (j < n ? j : 0)];
            float v = fmaxf(acc[u][0] + acc[u][1], 0.f);
            u64 key = ((u64)__float_as_uint(v) << 32) |
                      (unsigned int)(0xFFFFFFFFu - (unsigned int)p);
            #pragma unroll
            for (int off = 1; off < 64; off <<= 1) {
                u64 o = __shfl_xor(key, off, 64);
                key = key > o ? key : o;
            }
            if (lane == 0) atomicMax(&keys[b * CC + c], key);
        }
    }
}

// ---------------------------------------------------------------------------
// scatter: out[b, argmax_p(b,c), :] += W[c, :]
// ---------------------------------------------------------------------------
__global__ __launch_bounds__(64) void scatter_kernel(
    const u64* __restrict__ keys,
    const float* __restrict__ W,
    float* __restrict__ out)
{
    const int cell = blockIdx.x;
    const int c = cell & (CC - 1);
    const int b = cell >> 10;
    u64 key = keys[cell];
    unsigned int p = (0xFFFFFFFFu - (unsigned int)(key & 0xFFFFFFFFull)) & (PP - 1);

    const float* wrow = W + (size_t)c * DD;
    float* orow = out + ((size_t)b * PP + p) * DD;
    const int t = threadIdx.x;
    #pragma unroll
    for (int u = 0; u < 4; u++) {
        int idx = u * 64 + t;
        atomicAdd(&orow[idx], wrow[idx]);
    }
}

// ---------------------------------------------------------------------------
// fallback (ws too small): round-2 in-kernel-conversion kernel (verified)
// ---------------------------------------------------------------------------
__global__ __launch_bounds__(256, 2) void gemm_argmax_conv_kernel(
    const float* __restrict__ x, const float* __restrict__ W,
    u64* __restrict__ keys)
{
    __shared__ f16x8 lA[4][4][2][64];
    __shared__ f16x8 lB[4][4][2][64];

    const int tid = threadIdx.x;
    const int lane = tid & 63;
    const int w = tid >> 6;
    const int wy = w >> 1, wx = w & 1;
    const int p0 = blockIdx.x * 128;
    const int c0 = blockIdx.y * 128;
    const int b  = blockIdx.z;

    const float* xb = x + (size_t)b * PP * DD;

    f32x16 zero;
    #pragma unroll
    for (int i = 0; i < 16; ++i) zero[i] = 0.f;
    f32x16 acc_hi[2][2], acc_lo[2][2];
    #pragma unroll
    for (int i = 0; i < 2; ++i)
        #pragma unroll
        for (int j = 0; j < 2; ++j) { acc_hi[i][j] = zero; acc_lo[i][j] = zero; }

    for (int st = 0; st < 4; ++st) {
        const int k0 = st * 64;
        float4 gA[8], gB[8];
        #pragma unroll
        for (int v = 0; v < 4; ++v) {
            int pi = tid + 256 * v;
            int r  = pi >> 3;
            int ck = (pi & 7) * 8;
            const float* pa = xb + (size_t)(p0 + r) * DD + k0 + ck;
            gA[2 * v]     = *reinterpret_cast<const float4*>(pa);
            gA[2 * v + 1] = *reinterpret_cast<const float4*>(pa + 4);
            const float* pb = W + (size_t)(c0 + r) * DD + k0 + ck;
            gB[2 * v]     = *reinterpret_cast<const float4*>(pb);
            gB[2 * v + 1] = *reinterpret_cast<const float4*>(pb + 4);
        }
        __syncthreads();
        #pragma unroll
        for (int v = 0; v < 4; ++v) {
            int pi = tid + 256 * v;
            int r  = pi >> 3;
            int ph = pi & 7;
            int kk = ph >> 1;
            int half = ph & 1;
            int slot = (r & 31) + 32 * half;
            int rtp = r >> 5;
            float va[8] = {gA[2*v].x, gA[2*v].y, gA[2*v].z, gA[2*v].w,
                           gA[2*v+1].x, gA[2*v+1].y, gA[2*v+1].z, gA[2*v+1].w};
            f16x8 h1, h2;
            #pragma unroll
            for (int i = 0; i < 8; ++i) {
                _Float16 h = (_Float16)va[i];
                h1[i] = h;
                h2[i] = (_Float16)((va[i] - (float)h) * 4096.0f);
            }
            lA[kk][rtp][0][slot] = h1;
            lA[kk][rtp][1][slot] = h2;
            float vb[8] = {gB[2*v].x, gB[2*v].y, gB[2*v].z, gB[2*v].w,
                           gB[2*v+1].x, gB[2*v+1].y, gB[2*v+1].z, gB[2*v+1].w};
            f16x8 g1, g2;
            #pragma unroll
            for (int i = 0; i < 8; ++i) {
                _Float16 h = (_Float16)vb[i];
                g1[i] = h;
                g2[i] = (_Float16)((vb[i] - (float)h) * 4096.0f);
            }
            lB[kk][rtp][0][slot] = g1;
            lB[kk][rtp][1][slot] = g2;
        }
        __syncthreads();
        #pragma unroll
        for (int kk = 0; kk < 4; ++kk) {
            f16x8 xa[2][2], wb2[2][2];
            #pragma unroll
            for (int rt = 0; rt < 2; ++rt) {
                xa[rt][0] = lA[kk][wy * 2 + rt][0][lane];
                xa[rt][1] = lA[kk][wy * 2 + rt][1][lane];
            }
            #pragma unroll
            for (int ct = 0; ct < 2; ++ct) {
                wb2[ct][0] = lB[kk][wx * 2 + ct][0][lane];
                wb2[ct][1] = lB[kk][wx * 2 + ct][1][lane];
            }
            #pragma unroll
            for (int rt = 0; rt < 2; ++rt)
                #pragma unroll
                for (int ct = 0; ct < 2; ++ct) {
                    acc_hi[rt][ct] = __builtin_amdgcn_mfma_f32_32x32x16_f16(
                        xa[rt][0], wb2[ct][0], acc_hi[rt][ct], 0, 0, 0);
                    acc_lo[rt][ct] = __builtin_amdgcn_mfma_f32_32x32x16_f16(
                        xa[rt][0], wb2[ct][1], acc_lo[rt][ct], 0, 0, 0);
                    acc_lo[rt][ct] = __builtin_amdgcn_mfma_f32_32x32x16_f16(
                        xa[rt][1], wb2[ct][0], acc_lo[rt][ct], 0, 0, 0);
                }
        }
    }

    u64* smax = reinterpret_cast<u64*>(&lA[0][0][0][0]);
    __syncthreads();
    if (tid < 128) smax[tid] = 0ull;
    __syncthreads();

    #pragma unroll
    for (int ct = 0; ct < 2; ++ct) {
        u64 bk = 0ull;
        #pragma unroll
        for (int rt = 0; rt < 2; ++rt) {
            f32x16 h = acc_hi[rt][ct];
            f32x16 l = acc_lo[rt][ct];
            #pragma unroll
            for (int reg = 0; reg < 16; ++reg) {
                float v = fmaxf(h[reg] + l[reg] * (1.0f / 4096.0f), 0.f);
                int prow = p0 + (wy * 2 + rt) * 32 +
                           (reg & 3) + 8 * (reg >> 2) + 4 * (lane >> 5);
                u64 key = ((u64)__float_as_uint(v) << 32) |
                          (unsigned int)(0xFFFFFFFFu - (unsigned int)prow);
                bk = bk > key ? bk : key;
            }
        }
        u64 other = __shfl_xor(bk, 32, 64);
        bk = bk > other ? bk : other;
        if (lane < 32) {
            int col = (wx * 2 + ct) * 32 + (lane & 31);
            atomicMax(&smax[col], bk);
        }
    }
    __syncthreads();
    if (tid < 128) {
        atomicMax(&keys[(size_t)b * CC + c0 + tid], smax[tid]);
    }
}

extern "C" void kernel_launch(void* const* d_in, const int* in_sizes, int n_in,
                              void* d_out, int out_size, void* d_ws, size_t ws_size,
                              hipStream_t stream) {
    const float* x = (const float*)d_in[0];   // [B, P, D] fp32
    const float* W = (const float*)d_in[1];   // [C, D]    fp32
    float* out = (float*)d_out;

    char* wsb = (char*)d_ws;
    u64* keys    = (u64*)(wsb + WS_KEYS);
    u64* part_k1 = (u64*)(wsb + WS_PK);
    float* part_s2 = (float*)(wsb + WS_PS);
    int* cnt     = (int*)(wsb + WS_CNT);
    int* blist   = (int*)(wsb + WS_LIST);
    char* xT     = wsb + WS_XT;
    char* wT     = wsb + WS_WT;

    hipMemsetAsync(d_out, 0, (size_t)out_size * sizeof(float), stream);

    if (ws_size >= WS_NEED) {
        hipMemsetAsync(cnt, 0, 32, stream);
        transform_kernel<<<528, 256, 0, stream>>>(x, W, xT, wT);
        {
            dim3 grid(PP / 256, CC / 128, BB);
            pass1_kernel<<<grid, 256, 0, stream>>>(xT, wT, part_k1, part_s2);
        }
        finalize_kernel<<<32, 256, 0, stream>>>(part_k1, part_s2, keys, cnt, blist);
        {
            dim3 grid(64, BB);
            rescue_kernel<<<grid, 256, 0, stream>>>(x, W, cnt, blist, keys);
        }
    } else {
        int n = BB * CC;
        init_ws_kernel<<<(n + 255) / 256, 256, 0, stream>>>(keys, n);
        dim3 grid(PP / 128, CC / 128, BB);
        gemm_argmax_conv_kernel<<<grid, 256, 0, stream>>>(x, W, keys);
    }

    {
        dim3 grid(BB * CC);
        scatter_kernel<<<grid, 64, 0, stream>>>(keys, W, out);
    }
}